// Round 17
// baseline (2542.684 us; speedup 1.0000x reference)
//
#include <hip/hip_runtime.h>

#define TE 8    // edges per block (k_edge)
#define NT 16   // nodes per block (node kernels)

__device__ __forceinline__ float sigm(float x){ return 1.f / (1.f + __expf(-x)); }
__device__ __forceinline__ float siluf(float x){ return x / (1.f + __expf(-x)); }
__device__ __forceinline__ void atomAddF(float* p, float v){
  __hip_atomic_fetch_add(p, v, __ATOMIC_RELAXED, __HIP_MEMORY_SCOPE_AGENT);
}

// load EC consecutive f32 from LDS
template<int EC>
__device__ __forceinline__ void ldact(const float* p, float* av){
  if constexpr (EC >= 4){
    #pragma unroll
    for (int q = 0; q < EC/4; ++q){
      float4 t = *reinterpret_cast<const float4*>(p + 4*q);
      av[4*q+0]=t.x; av[4*q+1]=t.y; av[4*q+2]=t.z; av[4*q+3]=t.w;
    }
  } else if constexpr (EC == 2){
    float2 t = *reinterpret_cast<const float2*>(p);
    av[0]=t.x; av[1]=t.y;
  } else {
    av[0]=*p;
  }
}

__device__ __forceinline__ void ldw2(const float* W, int off, float* wv){
  float2 w = *reinterpret_cast<const float2*>(W + off);
  wv[0] = w.x; wv[1] = w.y;
}

// Tiled GEMV over a [K][TILE] transposed LDS activation tile.
template<int TILE, int K, int N, int NJ, int EG, class WL, class Post>
__device__ __forceinline__ void gemv_t(const float* pool, int actOff, int vtid,
                                       WL wload, Post post){
  constexpr int JT = N / NJ;
  constexpr int EC = TILE / EG;
  constexpr int ACT = JT * EG;
  static_assert(N % NJ == 0 && TILE % EG == 0, "bad cfg");
  if ((unsigned)vtid >= (unsigned)ACT) return;
  const int jt = vtid % JT, g = vtid / JT;
  const int j0 = jt * NJ, eb = g * EC;
  float acc[EC][NJ];
  #pragma unroll
  for (int e = 0; e < EC; ++e){
    #pragma unroll
    for (int t = 0; t < NJ; ++t) acc[e][t] = 0.f;
  }
  const float* ap = pool + actOff*TILE + eb;
  #pragma unroll 4
  for (int k = 0; k < K; ++k){
    float av[EC]; ldact<EC>(ap + k*TILE, av);
    float wv[NJ]; wload(k, j0, wv);
    #pragma unroll
    for (int t = 0; t < NJ; ++t){
      #pragma unroll
      for (int e = 0; e < EC; ++e)
        acc[e][t] = fmaf(av[e], wv[t], acc[e][t]);
    }
  }
  #pragma unroll
  for (int t = 0; t < NJ; ++t){
    #pragma unroll
    for (int e = 0; e < EC; ++e)
      post(j0 + t, eb + e, acc[e][t]);
  }
}

// ---------------- kernel 1: node pre-projections ----------------
__global__ __launch_bounds__(256) void k_node_pre(
    const float* __restrict__ node_input,
    const float* __restrict__ Wss, const float* __restrict__ bss,
    const float* __restrict__ Wsv,
    const float* __restrict__ Wds, const float* __restrict__ Wdv,
    float* __restrict__ msA, float* __restrict__ dsA,
    float* __restrict__ mvA, float* __restrict__ dvA)
{
  __shared__ __align__(16) float pl[320*NT];
  float* PL = pl;
  const int tid = threadIdx.x;
  const int n0 = blockIdx.x * NT;
  {
    int e = tid & 15, p = tid >> 4;
    const float* row = node_input + (size_t)(n0 + e)*320;
    for (int c = p; c < 128; c += 16) pl[c*NT + e] = row[c];
    for (int c = p; c < 64; c += 16){
      pl[(128 +       c)*NT + e] = row[128 + c*3 + 0];
      pl[(128 + 64  + c)*NT + e] = row[128 + c*3 + 1];
      pl[(128 + 128 + c)*NT + e] = row[128 + c*3 + 2];
    }
  }
  __syncthreads();
  gemv_t<NT,128,128,2,4>(PL, 0, tid,
    [=](int k,int j0,float* wv){ ldw2(Wss, k*128 + j0, wv); },
    [=](int j,int e,float v){ msA[(size_t)(n0+e)*128 + j] = bss[j] + v; });
  gemv_t<NT,128,128,2,4>(PL, 0, tid,
    [=](int k,int j0,float* wv){ ldw2(Wds, k*128 + j0, wv); },
    [=](int j,int e,float v){ dsA[(size_t)(n0+e)*128 + j] = v; });
  #pragma unroll
  for (int i = 0; i < 3; ++i){
    gemv_t<NT,64,64,2,8>(PL, 128 + i*64, tid,
      [=](int k,int j0,float* wv){ ldw2(Wsv, k*64 + j0, wv); },
      [=](int j,int e,float v){ mvA[(size_t)(n0+e)*192 + i*64 + j] = v; });
    gemv_t<NT,64,64,2,8>(PL, 128 + i*64, tid,
      [=](int k,int j0,float* wv){ ldw2(Wdv, k*64 + j0, wv); },
      [=](int j,int e,float v){ dvA[(size_t)(n0+e)*192 + i*64 + j] = v; });
  }
}

// ---------------- kernel 2: fused per-edge pipeline (TE=8) ----------------
// Region map (rows of TE floats), 960 rows = 30,720 B pool:
//  A 0..191   : ev (P2) -> EVW in-place (P4) -> S2 (P8)
//  B 192..383 : WF (P1,160) -> STP (P4) -> GV (P7)
//  C 384..575 : CRW (P4) -> FCR (P8)
//  D 576..703 : es (P2) -> FS (P6)
//  E 704..831 : T1A (P4) -> U1 (P7, rows 704..767)
//  F 832..895 : h2 (P3) -> T1 (P5)
//  G 896..959 : h1 (P2) -> GATE (P5)
__global__ __launch_bounds__(256, 4) void k_edge(
    const float* __restrict__ edge_attr, const float* __restrict__ edge_emb,
    const int* __restrict__ esrc, const int* __restrict__ edst,
    const float* __restrict__ node_attr,
    const float* __restrict__ msA, const float* __restrict__ dsA,
    const float* __restrict__ mvA, const float* __restrict__ dvA,
    const float* __restrict__ rW0, const float* __restrict__ rb0,
    const float* __restrict__ rW1, const float* __restrict__ rb1,
    const float* __restrict__ rW2, const float* __restrict__ rb2,
    const float* __restrict__ l1Ws, const float* __restrict__ l1bs, const float* __restrict__ l1Wv,
    const float* __restrict__ aWs, const float* __restrict__ abs_, const float* __restrict__ adot,
    const float* __restrict__ tp2w,
    const float* __restrict__ l2Ws, const float* __restrict__ l2bs, const float* __restrict__ l2Wv,
    float* __restrict__ den, float* __restrict__ num_s, float* __restrict__ num_v)
{
  constexpr int O_EV  = 0;
  constexpr int O_S2  = 0;
  constexpr int O_WF  = 192;
  constexpr int O_STP = 192;
  constexpr int O_GV  = 192;
  constexpr int O_CRW = 384;
  constexpr int O_FCR = 384;
  constexpr int O_ES  = 576;
  constexpr int O_GSA = 576;   // fs rows 0..127
  constexpr int O_T1A = 704;
  constexpr int O_U1B = 704;   // u1 rows 704..767 (over dead T1A head)
  constexpr int O_H2  = 832;
  constexpr int O_T1  = 832;
  constexpr int O_H1  = 896;
  constexpr int O_GSB = 896;   // gate rows 0..63

  __shared__ __align__(16) float pool[960*TE];
  __shared__ float y0s[TE], y1s[3*TE], zl[4*TE], lg[4*TE];
  __shared__ int srcI[TE], dstI[TE];

  float* PL = pool;
  float* ZL = zl;
  float* Y0 = y0s;
  int*   DI = dstI;

  const int tid = threadIdx.x;
  const int e0 = blockIdx.x * TE;

  if (tid < TE){ srcI[tid] = esrc[e0 + tid]; dstI[tid] = edst[e0 + tid]; }
  if (tid < 4*TE){
    int e = tid >> 2, q = tid & 3;
    float v = edge_attr[(size_t)(e0 + e)*4 + q];
    if (q == 0) y0s[e] = v; else y1s[(q-1)*TE + e] = v;
  }
  __syncthreads();

  { // P1: wf gather -> B (all 256; 5 elements each)
    int e = tid & 7, p = tid >> 3;  // p 0..31
    int si = srcI[e], di = dstI[e];
    for (int c = p; c < 160; c += 32){
      float v;
      if (c < 32)       v = edge_emb[(size_t)(e0+e)*32 + c];
      else if (c < 96)  v = node_attr[(size_t)si*64 + (c-32)];
      else              v = node_attr[(size_t)di*64 + (c-96)];
      pool[(O_WF + c)*TE + e] = v;
    }
  }
  __syncthreads();

  // P2: h1 (0..127, EG2) || es gather -> D (128..191) || ev gather -> A (192..255)
  if (tid < 128){
    gemv_t<TE,160,64,1,2>(PL, O_WF, tid,
      [=](int k,int j0,float* wv){ wv[0] = rW0[k*64 + j0]; },
      [=](int j,int e,float v){ PL[(O_H1 + j)*TE + e] = siluf(rb0[j] + v); });
  } else if (tid < 192){
    int r = tid - 128, e = r & 7, p = r >> 3;   // p 0..7
    const float* mp = msA + (size_t)srcI[e]*128;
    const float* dp = dsA + (size_t)dstI[e]*128;
    int c0 = p*16;
    #pragma unroll
    for (int q = 0; q < 4; ++q){
      float4 m = *reinterpret_cast<const float4*>(mp + c0 + q*4);
      float4 d = *reinterpret_cast<const float4*>(dp + c0 + q*4);
      pool[(O_ES + c0 + q*4 + 0)*TE + e] = m.x + d.x;
      pool[(O_ES + c0 + q*4 + 1)*TE + e] = m.y + d.y;
      pool[(O_ES + c0 + q*4 + 2)*TE + e] = m.z + d.z;
      pool[(O_ES + c0 + q*4 + 3)*TE + e] = m.w + d.w;
    }
  } else {
    int r = tid - 192, e = r & 7, p = r >> 3;  // p 0..7
    const float* mp = mvA + (size_t)srcI[e]*192;
    const float* dp = dvA + (size_t)dstI[e]*192;
    int c0 = p*8;
    #pragma unroll
    for (int i = 0; i < 3; ++i){
      #pragma unroll
      for (int q = 0; q < 2; ++q){
        float4 m = *reinterpret_cast<const float4*>(mp + i*64 + c0 + q*4);
        float4 d = *reinterpret_cast<const float4*>(dp + i*64 + c0 + q*4);
        pool[(O_EV + i*64 + c0 + q*4 + 0)*TE + e] = m.x + d.x;
        pool[(O_EV + i*64 + c0 + q*4 + 1)*TE + e] = m.y + d.y;
        pool[(O_EV + i*64 + c0 + q*4 + 2)*TE + e] = m.z + d.z;
        pool[(O_EV + i*64 + c0 + q*4 + 3)*TE + e] = m.w + d.w;
      }
    }
  }
  __syncthreads();

  // P3: h2 = silu(h1@rW1) -> F (0..127, EG2)
  if (tid < 128){
    gemv_t<TE,64,64,1,2>(PL, O_H1, tid,
      [=](int k,int j0,float* wv){ wv[0] = rW1[k*64 + j0]; },
      [=](int j,int e,float v){ PL[(O_H2 + j)*TE + e] = siluf(rb1[j] + v); });
  }
  __syncthreads();

  // P4: T1A (0..127, NJ1) || STP[0:128) (128..191, NJ2) || wdc (192..255)
  if (tid < 128){
    gemv_t<TE,64,128,1,1>(PL, O_H2, tid,
      [=](int k,int j0,float* wv){ wv[0] = rW2[k*448 + 128 + j0]; },
      [=](int j,int e,float v){
        PL[(O_T1A + j)*TE + e] = (rb2[128 + j] + v) * PL[(O_ES + j)*TE + e];
      });
  } else if (tid < 192){
    gemv_t<TE,64,128,2,1>(PL, O_H2, tid - 128,
      [=](int k,int j0,float* wv){ ldw2(rW2, k*448 + j0, wv); },
      [=](int j,int e,float v){
        PL[(O_STP + j)*TE + e] = (rb2[j] + v) * PL[(O_ES + j)*TE + e] * Y0[e];
      });
  } else {
    int c = tid - 192;                 // 0..63
    float avs[TE], adt[TE], acr[TE];
    #pragma unroll
    for (int e = 0; e < TE; ++e){ avs[e]=0.f; adt[e]=0.f; acr[e]=0.f; }
    const float* hp = PL + O_H2*TE;
    #pragma unroll 4
    for (int k = 0; k < 64; ++k){
      float av[TE]; ldact<TE>(hp + k*TE, av);
      float wv = rW2[k*448 + 256 + c];
      float wd = rW2[k*448 + 320 + c];
      float wc = rW2[k*448 + 384 + c];
      #pragma unroll
      for (int e = 0; e < TE; ++e){
        avs[e] = fmaf(av[e], wv, avs[e]);
        adt[e] = fmaf(av[e], wd, adt[e]);
        acr[e] = fmaf(av[e], wc, acr[e]);
      }
    }
    float bvs = rb2[256+c], bdt = rb2[320+c], bcr = rb2[384+c];
    #pragma unroll
    for (int e = 0; e < TE; ++e){
      float wvs = avs[e]+bvs, wdt = adt[e]+bdt, wcr = acr[e]+bcr;
      float ev0 = pool[(O_EV +       c)*TE + e];
      float ev1 = pool[(O_EV + 64  + c)*TE + e];
      float ev2 = pool[(O_EV + 128 + c)*TE + e];
      float y10 = y1s[e], y11 = y1s[TE + e], y12 = y1s[2*TE + e];
      pool[(O_STP + 128 + c)*TE + e] = wdt * (ev0*y10 + ev1*y11 + ev2*y12);
      pool[(O_EV +       c)*TE + e] = wvs * ev0;
      pool[(O_EV + 64  + c)*TE + e] = wvs * ev1;
      pool[(O_EV + 128 + c)*TE + e] = wvs * ev2;
      pool[(O_CRW +       c)*TE + e] = wcr * (ev1*y12 - ev2*y11);
      pool[(O_CRW + 64  + c)*TE + e] = wcr * (ev2*y10 - ev0*y12);
      pool[(O_CRW + 128 + c)*TE + e] = wcr * (ev0*y11 - ev1*y10);
    }
  }
  __syncthreads();

  // P5: att logits (0..127, NJ1) || gate (128..191) || t1 (192..255)
  if (tid < 128){
    int j = tid;
    float acc[TE];
    #pragma unroll
    for (int e = 0; e < TE; ++e) acc[e] = 0.f;
    const float* ap = PL + O_STP*TE;
    #pragma unroll 4
    for (int k = 0; k < 192; ++k){
      float av[TE]; ldact<TE>(ap + k*TE, av);
      float w = aWs[k*128 + j];
      #pragma unroll
      for (int e = 0; e < TE; ++e) acc[e] = fmaf(av[e], w, acc[e]);
    }
    float bb = abs_[j], dt = adot[j];
    int h = j >> 5;
    #pragma unroll
    for (int e = 0; e < TE; ++e){
      float t = acc[e] + bb;
      float c = t * (0.2f + 0.8f*sigm(t)) * dt;   // smooth_leaky * adot
      c += __shfl_xor(c, 1, 32);
      c += __shfl_xor(c, 2, 32);
      c += __shfl_xor(c, 4, 32);
      c += __shfl_xor(c, 8, 32);
      c += __shfl_xor(c, 16, 32);
      if ((j & 31) == 0) lg[h*TE + e] = c;
    }
  } else if (tid < 192){
    gemv_t<TE,192,64,1,1>(PL, O_STP, tid - 128,
      [=](int k,int j0,float* wv){ wv[0] = l1Ws[k*192 + 128 + j0]; },
      [=](int j,int e,float v){ PL[(O_GSB + j)*TE + e] = sigm(l1bs[128 + j] + v); });
  } else {
    gemv_t<TE,128,64,1,1>(PL, O_T1A, tid - 192,
      [=](int k,int j0,float* wv){ wv[0] = l1Wv[k*64 + j0]; },
      [=](int j,int e,float v){ PL[(O_T1 + j)*TE + e] = v; });
  }
  __syncthreads();

  // P6: fs = silu(STP@l1Ws[:,0:128) + b) -> D (all 256, EG2)
  gemv_t<TE,192,128,1,2>(PL, O_STP, tid,
    [=](int k,int j0,float* wv){ wv[0] = l1Ws[k*192 + j0]; },
    [=](int j,int e,float v){ PL[(O_GSA + j)*TE + e] = siluf(l1bs[j] + v); });
  __syncthreads();

  // P7: gv (0..191, 1 col each): fv = (y1*T1 + y0*(EVW@Wv2) + CRW@Wv3)*gate
  //     || u1 (192..255): (tp2_sv*FS)@l2Wv[0:128) -> E
  if (tid < 192){
    int i = tid >> 6, d = tid & 63;
    float accP[TE], accY[TE];
    #pragma unroll
    for (int e = 0; e < TE; ++e){
      accP[e] = y1s[i*TE + e] * pool[(O_T1 + d)*TE + e];
      accY[e] = 0.f;
    }
    #pragma unroll 2
    for (int k = 0; k < 64; ++k){
      float av[TE], cv[TE];
      ldact<TE>(&pool[(O_EV  + i*64 + k)*TE], av);
      ldact<TE>(&pool[(O_CRW + i*64 + k)*TE], cv);
      float w2 = l1Wv[(128 + k)*64 + d];
      float w3 = l1Wv[(192 + k)*64 + d];
      #pragma unroll
      for (int e = 0; e < TE; ++e){
        accY[e] = fmaf(av[e], w2, accY[e]);
        accP[e] = fmaf(cv[e], w3, accP[e]);
      }
    }
    #pragma unroll
    for (int e = 0; e < TE; ++e){
      float val = accP[e] + y0s[e]*accY[e];
      pool[(O_GV + i*64 + d)*TE + e] = val * pool[(O_GSB + d)*TE + e];
    }
  } else {
    gemv_t<TE,128,64,1,1>(PL, O_GSA, tid - 192,
      [=](int k,int j0,float* wv){ wv[0] = tp2w[128 + k] * l2Wv[k*64 + j0]; },
      [=](int j,int e,float v){ PL[(O_U1B + j)*TE + e] = v; });
  }
  __syncthreads();

  // ---- P8/P9 with register-carried val_v GV-part (threads 160..255) ----
  float vvY[TE][2];

  // P8: s2 -> A, fcr -> C (0..127) || z,den (128..159) || val_v GV-part (160..255)
  if (tid < 128){
    int e = tid & 7, p = tid >> 3;   // p 0..15
    float yy0 = y0s[e];
    float y10 = y1s[e], y11 = y1s[TE + e], y12 = y1s[2*TE + e];
    for (int c = p; c < 128; c += 16){
      pool[(O_S2 + c)*TE + e] = tp2w[c] * pool[(O_GSA + c)*TE + e] * yy0;
    }
    for (int c = p; c < 64; c += 16){
      float f0 = pool[(O_GV +       c)*TE + e];
      float f1 = pool[(O_GV + 64  + c)*TE + e];
      float f2 = pool[(O_GV + 128 + c)*TE + e];
      pool[(O_S2 + 128 + c)*TE + e] = tp2w[320 + c] * (f0*y10 + f1*y11 + f2*y12);
      pool[(O_FCR +       c)*TE + e] = f1*y12 - f2*y11;
      pool[(O_FCR + 64  + c)*TE + e] = f2*y10 - f0*y12;
      pool[(O_FCR + 128 + c)*TE + e] = f0*y11 - f1*y10;
    }
  } else if (tid < 160){
    int r = tid - 128, e = r & 7, h = r >> 3;
    float z = __expf(lg[h*TE + e]);            // max-free; logits O(few) << 88
    zl[h*TE + e] = z;
    atomAddF(&den[(size_t)dstI[e]*4 + h], z);
  } else {
    int r = tid - 160;             // 0..95
    int i = r / 32, d0 = (r % 32) * 2;
    #pragma unroll
    for (int e = 0; e < TE; ++e){ vvY[e][0] = 0.f; vvY[e][1] = 0.f; }
    #pragma unroll 2
    for (int k = 0; k < 64; ++k){
      float av[TE]; ldact<TE>(&pool[(O_GV + i*64 + k)*TE], av);
      float w2[2];
      float s2c = tp2w[256 + k];
      ldw2(l2Wv, (128 + k)*64 + d0, w2);
      w2[0]*=s2c; w2[1]*=s2c;
      #pragma unroll
      for (int e = 0; e < TE; ++e){
        vvY[e][0] = fmaf(av[e], w2[0], vvY[e][0]);
        vvY[e][1] = fmaf(av[e], w2[1], vvY[e][1]);
      }
    }
  }
  __syncthreads();

  // P9: val_s scatter (0..127, NJ1) || val_v FCR-part + scatter (160..255)
  if (tid < 128){
    gemv_t<TE,192,128,1,1>(PL, O_S2, tid,
      [=](int k,int j0,float* wv){ wv[0] = l2Ws[k*128 + j0]; },
      [=](int j,int e,float v){
        float vv = (l2bs[j] + v) * ZL[(j >> 5)*TE + e];
        atomAddF(&num_s[(size_t)DI[e]*128 + j], vv);
      });
  } else if (tid >= 160){
    int r = tid - 160;
    int i = r / 32, d0 = (r % 32) * 2;
    float accP[TE][2];
    #pragma unroll
    for (int e = 0; e < TE; ++e){
      float y1v = y1s[i*TE + e];
      accP[e][0] = y1v * pool[(O_U1B + d0    )*TE + e];
      accP[e][1] = y1v * pool[(O_U1B + d0 + 1)*TE + e];
    }
    #pragma unroll 2
    for (int k = 0; k < 64; ++k){
      float cv[TE]; ldact<TE>(&pool[(O_FCR + i*64 + k)*TE], cv);
      float w3[2];
      float s3c = tp2w[384 + k];
      ldw2(l2Wv, (192 + k)*64 + d0, w3);
      w3[0]*=s3c; w3[1]*=s3c;
      #pragma unroll
      for (int e = 0; e < TE; ++e){
        accP[e][0] = fmaf(cv[e], w3[0], accP[e][0]);
        accP[e][1] = fmaf(cv[e], w3[1], accP[e][1]);
      }
    }
    #pragma unroll
    for (int t = 0; t < 2; ++t){
      int d = d0 + t;
      int h = d >> 4;
      #pragma unroll
      for (int e = 0; e < TE; ++e){
        float val = accP[e][t] + y0s[e]*vvY[e][t];
        atomAddF(&num_v[(size_t)dstI[e]*192 + i*64 + d], val * zl[h*TE + e]);
      }
    }
  }
}

// ---------------- kernel 3: normalize + output projections ----------------
__global__ __launch_bounds__(256) void k_node_out(
    const float* __restrict__ den, const float* __restrict__ num_s, const float* __restrict__ num_v,
    const float* __restrict__ Wos, const float* __restrict__ bos, const float* __restrict__ Wov,
    float* __restrict__ out)
{
  __shared__ __align__(16) float pl[320*NT];
  __shared__ float dl[4*NT];
  float* PL = pl;
  const int tid = threadIdx.x;
  const int n0 = blockIdx.x * NT;
  if (tid < 64){
    int e = tid & 15, h = tid >> 4;
    dl[h*NT + e] = den[(size_t)(n0 + e)*4 + h] + 1e-12f;
  }
  __syncthreads();
  {
    int e = tid & 15, p = tid >> 4;
    for (int c = p; c < 128; c += 16)
      pl[c*NT + e] = num_s[(size_t)(n0+e)*128 + c] / dl[(c >> 5)*NT + e];
    for (int c = p; c < 64; c += 16){
      float dd = dl[(c >> 4)*NT + e];
      pl[(128 +       c)*NT + e] = num_v[(size_t)(n0+e)*192 +       c] / dd;
      pl[(128 + 64  + c)*NT + e] = num_v[(size_t)(n0+e)*192 + 64  + c] / dd;
      pl[(128 + 128 + c)*NT + e] = num_v[(size_t)(n0+e)*192 + 128 + c] / dd;
    }
  }
  __syncthreads();
  gemv_t<NT,128,128,2,4>(PL, 0, tid,
    [=](int k,int j0,float* wv){ ldw2(Wos, k*128 + j0, wv); },
    [=](int j,int e,float v){ out[(size_t)(n0+e)*320 + j] = bos[j] + v; });
  #pragma unroll
  for (int i = 0; i < 3; ++i){
    gemv_t<NT,64,64,2,8>(PL, 128 + i*64, tid,
      [=](int k,int j0,float* wv){ ldw2(Wov, k*64 + j0, wv); },
      [=](int j,int e,float v){ out[(size_t)(n0+e)*320 + 128 + j*3 + i] = v; });
  }
}

extern "C" void kernel_launch(void* const* d_in, const int* in_sizes, int n_in,
                              void* d_out, int out_size, void* d_ws, size_t ws_size,
                              hipStream_t stream)
{
  const float* node_input = (const float*)d_in[0];
  const float* node_attr  = (const float*)d_in[1];
  const float* edge_attr  = (const float*)d_in[2];
  const float* edge_emb   = (const float*)d_in[3];
  const int* edge_src   = (const int*)d_in[4];
  const int* edge_dst   = (const int*)d_in[5];
  const float* W_src_s = (const float*)d_in[6];
  const float* b_src_s = (const float*)d_in[7];
  const float* W_src_v = (const float*)d_in[8];
  const float* W_dst_s = (const float*)d_in[9];
  const float* W_dst_v = (const float*)d_in[10];
  const float* rad_W0  = (const float*)d_in[11];
  const float* rad_b0  = (const float*)d_in[12];
  const float* rad_W1  = (const float*)d_in[13];
  const float* rad_b1  = (const float*)d_in[14];
  const float* rad_W2  = (const float*)d_in[15];
  const float* rad_b2  = (const float*)d_in[16];
  const float* lin1_Ws = (const float*)d_in[17];
  const float* lin1_bs = (const float*)d_in[18];
  const float* lin1_Wv = (const float*)d_in[19];
  const float* att_Ws  = (const float*)d_in[20];
  const float* att_bs  = (const float*)d_in[21];
  const float* tp2_w   = (const float*)d_in[22];
  const float* lin2_Ws = (const float*)d_in[23];
  const float* lin2_bs = (const float*)d_in[24];
  const float* lin2_Wv = (const float*)d_in[25];
  const float* att_dot = (const float*)d_in[26];
  const float* out_Ws  = (const float*)d_in[27];
  const float* out_bs  = (const float*)d_in[28];
  const float* out_Wv  = (const float*)d_in[29];

  const int nN = in_sizes[0] / 320;   // 10000
  const int nE = in_sizes[4];         // 320000

  float* ws    = (float*)d_ws;
  float* den   = ws;
  float* num_s = den   + (size_t)nN * 4;
  float* num_v = num_s + (size_t)nN * 128;
  float* msA   = num_v + (size_t)nN * 192;
  float* dsA   = msA   + (size_t)nN * 128;
  float* mvA   = dsA   + (size_t)nN * 128;
  float* dvA   = mvA   + (size_t)nN * 192;

  size_t need = ((size_t)nN * (4 + 128 + 192 + 128 + 128 + 192 + 192)) * sizeof(float);
  if (ws_size < need) return;  // fail loudly (output stays poisoned)

  hipMemsetAsync(den, 0, (size_t)nN * (4 + 128 + 192) * sizeof(float), stream);

  k_node_pre<<<nN/NT, 256, 0, stream>>>(node_input, W_src_s, b_src_s, W_src_v,
                                        W_dst_s, W_dst_v, msA, dsA, mvA, dvA);
  k_edge<<<nE/TE, 256, 0, stream>>>(edge_attr, edge_emb, edge_src, edge_dst, node_attr,
                                    msA, dsA, mvA, dvA,
                                    rad_W0, rad_b0, rad_W1, rad_b1, rad_W2, rad_b2,
                                    lin1_Ws, lin1_bs, lin1_Wv,
                                    att_Ws, att_bs, att_dot,
                                    tp2_w, lin2_Ws, lin2_bs, lin2_Wv,
                                    den, num_s, num_v);
  k_node_out<<<nN/NT, 256, 0, stream>>>(den, num_s, num_v, out_Ws, out_bs, out_Wv,
                                        (float*)d_out);
}

// Round 18
// 2466.317 us; speedup vs baseline: 1.0310x; 1.0310x over previous
//
#include <hip/hip_runtime.h>

#define TE 8    // edges per block (k_edge)
#define NT 16   // nodes per block (node kernels)

__device__ __forceinline__ float sigm(float x){ return 1.f / (1.f + __expf(-x)); }
__device__ __forceinline__ float siluf(float x){ return x / (1.f + __expf(-x)); }
__device__ __forceinline__ void atomAddF(float* p, float v){
  __hip_atomic_fetch_add(p, v, __ATOMIC_RELAXED, __HIP_MEMORY_SCOPE_AGENT);
}

// load EC consecutive f32 from LDS
template<int EC>
__device__ __forceinline__ void ldact(const float* p, float* av){
  if constexpr (EC >= 4){
    #pragma unroll
    for (int q = 0; q < EC/4; ++q){
      float4 t = *reinterpret_cast<const float4*>(p + 4*q);
      av[4*q+0]=t.x; av[4*q+1]=t.y; av[4*q+2]=t.z; av[4*q+3]=t.w;
    }
  } else if constexpr (EC == 2){
    float2 t = *reinterpret_cast<const float2*>(p);
    av[0]=t.x; av[1]=t.y;
  } else {
    av[0]=*p;
  }
}

__device__ __forceinline__ void ldw2(const float* W, int off, float* wv){
  float2 w = *reinterpret_cast<const float2*>(W + off);
  wv[0] = w.x; wv[1] = w.y;
}

// Tiled GEMV over a [K][TILE] transposed LDS activation tile.
template<int TILE, int K, int N, int NJ, int EG, class WL, class Post>
__device__ __forceinline__ void gemv_t(const float* pool, int actOff, int vtid,
                                       WL wload, Post post){
  constexpr int JT = N / NJ;
  constexpr int EC = TILE / EG;
  constexpr int ACT = JT * EG;
  static_assert(N % NJ == 0 && TILE % EG == 0, "bad cfg");
  if ((unsigned)vtid >= (unsigned)ACT) return;
  const int jt = vtid % JT, g = vtid / JT;
  const int j0 = jt * NJ, eb = g * EC;
  float acc[EC][NJ];
  #pragma unroll
  for (int e = 0; e < EC; ++e){
    #pragma unroll
    for (int t = 0; t < NJ; ++t) acc[e][t] = 0.f;
  }
  const float* ap = pool + actOff*TILE + eb;
  #pragma unroll 4
  for (int k = 0; k < K; ++k){
    float av[EC]; ldact<EC>(ap + k*TILE, av);
    float wv[NJ]; wload(k, j0, wv);
    #pragma unroll
    for (int t = 0; t < NJ; ++t){
      #pragma unroll
      for (int e = 0; e < EC; ++e)
        acc[e][t] = fmaf(av[e], wv[t], acc[e][t]);
    }
  }
  #pragma unroll
  for (int t = 0; t < NJ; ++t){
    #pragma unroll
    for (int e = 0; e < EC; ++e)
      post(j0 + t, eb + e, acc[e][t]);
  }
}

// ---------------- kernel 1: node pre-projections ----------------
__global__ __launch_bounds__(256) void k_node_pre(
    const float* __restrict__ node_input,
    const float* __restrict__ Wss, const float* __restrict__ bss,
    const float* __restrict__ Wsv,
    const float* __restrict__ Wds, const float* __restrict__ Wdv,
    float* __restrict__ msA, float* __restrict__ dsA,
    float* __restrict__ mvA, float* __restrict__ dvA)
{
  __shared__ __align__(16) float pl[320*NT];
  float* PL = pl;
  const int tid = threadIdx.x;
  const int n0 = blockIdx.x * NT;
  {
    int e = tid & 15, p = tid >> 4;
    const float* row = node_input + (size_t)(n0 + e)*320;
    for (int c = p; c < 128; c += 16) pl[c*NT + e] = row[c];
    for (int c = p; c < 64; c += 16){
      pl[(128 +       c)*NT + e] = row[128 + c*3 + 0];
      pl[(128 + 64  + c)*NT + e] = row[128 + c*3 + 1];
      pl[(128 + 128 + c)*NT + e] = row[128 + c*3 + 2];
    }
  }
  __syncthreads();
  gemv_t<NT,128,128,2,4>(PL, 0, tid,
    [=](int k,int j0,float* wv){ ldw2(Wss, k*128 + j0, wv); },
    [=](int j,int e,float v){ msA[(size_t)(n0+e)*128 + j] = bss[j] + v; });
  gemv_t<NT,128,128,2,4>(PL, 0, tid,
    [=](int k,int j0,float* wv){ ldw2(Wds, k*128 + j0, wv); },
    [=](int j,int e,float v){ dsA[(size_t)(n0+e)*128 + j] = v; });
  #pragma unroll
  for (int i = 0; i < 3; ++i){
    gemv_t<NT,64,64,2,8>(PL, 128 + i*64, tid,
      [=](int k,int j0,float* wv){ ldw2(Wsv, k*64 + j0, wv); },
      [=](int j,int e,float v){ mvA[(size_t)(n0+e)*192 + i*64 + j] = v; });
    gemv_t<NT,64,64,2,8>(PL, 128 + i*64, tid,
      [=](int k,int j0,float* wv){ ldw2(Wdv, k*64 + j0, wv); },
      [=](int j,int e,float v){ dvA[(size_t)(n0+e)*192 + i*64 + j] = v; });
  }
}

// ---------------- kernel 2: fused per-edge pipeline (TE=8) ----------------
// Region map (rows of TE floats), 960 rows = 30,720 B pool:
//  A 0..191   : ev (P2) -> EVW in-place (P4) -> S2 (P8)
//  B 192..383 : WF (P1,160) -> STP (P4) -> GV (P7)
//  C 384..575 : CRW (P4) -> FCR (P8)
//  D 576..703 : es (P2) -> FS (P6)
//  E 704..831 : T1A (P4) -> U1 (P7, rows 704..767)
//  F 832..895 : h2 (P3) -> T1 (P5)
//  G 896..959 : h1 (P2) -> GATE (P5)
__global__ __launch_bounds__(256, 4) void k_edge(
    const float* __restrict__ edge_attr, const float* __restrict__ edge_emb,
    const int* __restrict__ esrc, const int* __restrict__ edst,
    const float* __restrict__ node_attr,
    const float* __restrict__ msA, const float* __restrict__ dsA,
    const float* __restrict__ mvA, const float* __restrict__ dvA,
    const float* __restrict__ rW0, const float* __restrict__ rb0,
    const float* __restrict__ rW1, const float* __restrict__ rb1,
    const float* __restrict__ rW2, const float* __restrict__ rb2,
    const float* __restrict__ l1Ws, const float* __restrict__ l1bs, const float* __restrict__ l1Wv,
    const float* __restrict__ aWs, const float* __restrict__ abs_, const float* __restrict__ adot,
    const float* __restrict__ tp2w,
    const float* __restrict__ l2Ws, const float* __restrict__ l2bs, const float* __restrict__ l2Wv,
    float* __restrict__ den, float* __restrict__ num_s, float* __restrict__ num_v)
{
  constexpr int O_EV  = 0;
  constexpr int O_S2  = 0;
  constexpr int O_WF  = 192;
  constexpr int O_STP = 192;
  constexpr int O_GV  = 192;
  constexpr int O_CRW = 384;
  constexpr int O_FCR = 384;
  constexpr int O_ES  = 576;
  constexpr int O_GSA = 576;   // fs rows 0..127
  constexpr int O_T1A = 704;
  constexpr int O_U1B = 704;   // u1 rows 704..767 (over dead T1A head)
  constexpr int O_H2  = 832;
  constexpr int O_T1  = 832;
  constexpr int O_H1  = 896;
  constexpr int O_GSB = 896;   // gate rows 0..63

  __shared__ __align__(16) float pool[960*TE];
  __shared__ float y0s[TE], y1s[3*TE], zl[4*TE], lg[4*TE];
  __shared__ int srcI[TE], dstI[TE];

  float* PL = pool;
  float* ZL = zl;
  float* Y0 = y0s;
  int*   DI = dstI;

  const int tid = threadIdx.x;
  const int e0 = blockIdx.x * TE;

  if (tid < TE){ srcI[tid] = esrc[e0 + tid]; dstI[tid] = edst[e0 + tid]; }
  if (tid < 4*TE){
    int e = tid >> 2, q = tid & 3;
    float v = edge_attr[(size_t)(e0 + e)*4 + q];
    if (q == 0) y0s[e] = v; else y1s[(q-1)*TE + e] = v;
  }
  __syncthreads();

  { // P1: wf gather -> B (all 256; 5 elements each)
    int e = tid & 7, p = tid >> 3;  // p 0..31
    int si = srcI[e], di = dstI[e];
    for (int c = p; c < 160; c += 32){
      float v;
      if (c < 32)       v = edge_emb[(size_t)(e0+e)*32 + c];
      else if (c < 96)  v = node_attr[(size_t)si*64 + (c-32)];
      else              v = node_attr[(size_t)di*64 + (c-96)];
      pool[(O_WF + c)*TE + e] = v;
    }
  }
  __syncthreads();

  // P2: h1 (0..127, EG2) || es gather -> D (128..191) || ev gather -> A (192..255)
  if (tid < 128){
    gemv_t<TE,160,64,1,2>(PL, O_WF, tid,
      [=](int k,int j0,float* wv){ wv[0] = rW0[k*64 + j0]; },
      [=](int j,int e,float v){ PL[(O_H1 + j)*TE + e] = siluf(rb0[j] + v); });
  } else if (tid < 192){
    int r = tid - 128, e = r & 7, p = r >> 3;   // p 0..7
    const float* mp = msA + (size_t)srcI[e]*128;
    const float* dp = dsA + (size_t)dstI[e]*128;
    int c0 = p*16;
    #pragma unroll
    for (int q = 0; q < 4; ++q){
      float4 m = *reinterpret_cast<const float4*>(mp + c0 + q*4);
      float4 d = *reinterpret_cast<const float4*>(dp + c0 + q*4);
      pool[(O_ES + c0 + q*4 + 0)*TE + e] = m.x + d.x;
      pool[(O_ES + c0 + q*4 + 1)*TE + e] = m.y + d.y;
      pool[(O_ES + c0 + q*4 + 2)*TE + e] = m.z + d.z;
      pool[(O_ES + c0 + q*4 + 3)*TE + e] = m.w + d.w;
    }
  } else {
    int r = tid - 192, e = r & 7, p = r >> 3;  // p 0..7
    const float* mp = mvA + (size_t)srcI[e]*192;
    const float* dp = dvA + (size_t)dstI[e]*192;
    int c0 = p*8;
    #pragma unroll
    for (int i = 0; i < 3; ++i){
      #pragma unroll
      for (int q = 0; q < 2; ++q){
        float4 m = *reinterpret_cast<const float4*>(mp + i*64 + c0 + q*4);
        float4 d = *reinterpret_cast<const float4*>(dp + i*64 + c0 + q*4);
        pool[(O_EV + i*64 + c0 + q*4 + 0)*TE + e] = m.x + d.x;
        pool[(O_EV + i*64 + c0 + q*4 + 1)*TE + e] = m.y + d.y;
        pool[(O_EV + i*64 + c0 + q*4 + 2)*TE + e] = m.z + d.z;
        pool[(O_EV + i*64 + c0 + q*4 + 3)*TE + e] = m.w + d.w;
      }
    }
  }
  __syncthreads();

  // P3: h2 = silu(h1@rW1) -> F (0..127, EG2)
  if (tid < 128){
    gemv_t<TE,64,64,1,2>(PL, O_H1, tid,
      [=](int k,int j0,float* wv){ wv[0] = rW1[k*64 + j0]; },
      [=](int j,int e,float v){ PL[(O_H2 + j)*TE + e] = siluf(rb1[j] + v); });
  }
  __syncthreads();

  // P4: T1A (0..127, NJ1) || STP[0:128) (128..191, NJ2) || wdc (192..255)
  if (tid < 128){
    gemv_t<TE,64,128,1,1>(PL, O_H2, tid,
      [=](int k,int j0,float* wv){ wv[0] = rW2[k*448 + 128 + j0]; },
      [=](int j,int e,float v){
        PL[(O_T1A + j)*TE + e] = (rb2[128 + j] + v) * PL[(O_ES + j)*TE + e];
      });
  } else if (tid < 192){
    gemv_t<TE,64,128,2,1>(PL, O_H2, tid - 128,
      [=](int k,int j0,float* wv){ ldw2(rW2, k*448 + j0, wv); },
      [=](int j,int e,float v){
        PL[(O_STP + j)*TE + e] = (rb2[j] + v) * PL[(O_ES + j)*TE + e] * Y0[e];
      });
  } else {
    int c = tid - 192;                 // 0..63
    float avs[TE], adt[TE], acr[TE];
    #pragma unroll
    for (int e = 0; e < TE; ++e){ avs[e]=0.f; adt[e]=0.f; acr[e]=0.f; }
    const float* hp = PL + O_H2*TE;
    #pragma unroll 4
    for (int k = 0; k < 64; ++k){
      float av[TE]; ldact<TE>(hp + k*TE, av);
      float wv = rW2[k*448 + 256 + c];
      float wd = rW2[k*448 + 320 + c];
      float wc = rW2[k*448 + 384 + c];
      #pragma unroll
      for (int e = 0; e < TE; ++e){
        avs[e] = fmaf(av[e], wv, avs[e]);
        adt[e] = fmaf(av[e], wd, adt[e]);
        acr[e] = fmaf(av[e], wc, acr[e]);
      }
    }
    float bvs = rb2[256+c], bdt = rb2[320+c], bcr = rb2[384+c];
    #pragma unroll
    for (int e = 0; e < TE; ++e){
      float wvs = avs[e]+bvs, wdt = adt[e]+bdt, wcr = acr[e]+bcr;
      float ev0 = pool[(O_EV +       c)*TE + e];
      float ev1 = pool[(O_EV + 64  + c)*TE + e];
      float ev2 = pool[(O_EV + 128 + c)*TE + e];
      float y10 = y1s[e], y11 = y1s[TE + e], y12 = y1s[2*TE + e];
      pool[(O_STP + 128 + c)*TE + e] = wdt * (ev0*y10 + ev1*y11 + ev2*y12);
      pool[(O_EV +       c)*TE + e] = wvs * ev0;
      pool[(O_EV + 64  + c)*TE + e] = wvs * ev1;
      pool[(O_EV + 128 + c)*TE + e] = wvs * ev2;
      pool[(O_CRW +       c)*TE + e] = wcr * (ev1*y12 - ev2*y11);
      pool[(O_CRW + 64  + c)*TE + e] = wcr * (ev2*y10 - ev0*y12);
      pool[(O_CRW + 128 + c)*TE + e] = wcr * (ev0*y11 - ev1*y10);
    }
  }
  __syncthreads();

  // P5: att logits (0..127, NJ1) || gate (128..191) || t1 (192..255)
  if (tid < 128){
    int j = tid;
    float acc[TE];
    #pragma unroll
    for (int e = 0; e < TE; ++e) acc[e] = 0.f;
    const float* ap = PL + O_STP*TE;
    #pragma unroll 4
    for (int k = 0; k < 192; ++k){
      float av[TE]; ldact<TE>(ap + k*TE, av);
      float w = aWs[k*128 + j];
      #pragma unroll
      for (int e = 0; e < TE; ++e) acc[e] = fmaf(av[e], w, acc[e]);
    }
    float bb = abs_[j], dt = adot[j];
    int h = j >> 5;
    #pragma unroll
    for (int e = 0; e < TE; ++e){
      float t = acc[e] + bb;
      float c = t * (0.2f + 0.8f*sigm(t)) * dt;   // smooth_leaky * adot
      c += __shfl_xor(c, 1, 32);
      c += __shfl_xor(c, 2, 32);
      c += __shfl_xor(c, 4, 32);
      c += __shfl_xor(c, 8, 32);
      c += __shfl_xor(c, 16, 32);
      if ((j & 31) == 0) lg[h*TE + e] = c;
    }
  } else if (tid < 192){
    gemv_t<TE,192,64,1,1>(PL, O_STP, tid - 128,
      [=](int k,int j0,float* wv){ wv[0] = l1Ws[k*192 + 128 + j0]; },
      [=](int j,int e,float v){ PL[(O_GSB + j)*TE + e] = sigm(l1bs[128 + j] + v); });
  } else {
    gemv_t<TE,128,64,1,1>(PL, O_T1A, tid - 192,
      [=](int k,int j0,float* wv){ wv[0] = l1Wv[k*64 + j0]; },
      [=](int j,int e,float v){ PL[(O_T1 + j)*TE + e] = v; });
  }
  __syncthreads();

  // P6: fs = silu(STP@l1Ws[:,0:128) + b) -> D (all 256, EG2)
  gemv_t<TE,192,128,1,2>(PL, O_STP, tid,
    [=](int k,int j0,float* wv){ wv[0] = l1Ws[k*192 + j0]; },
    [=](int j,int e,float v){ PL[(O_GSA + j)*TE + e] = siluf(l1bs[j] + v); });
  __syncthreads();

  // P7: gv (0..191, 1 col each): fv = (y1*T1 + y0*(EVW@Wv2) + CRW@Wv3)*gate
  //     || u1 (192..255): (tp2_sv*FS)@l2Wv[0:128) -> E
  if (tid < 192){
    int i = tid >> 6, d = tid & 63;
    float accP[TE], accY[TE];
    #pragma unroll
    for (int e = 0; e < TE; ++e){
      accP[e] = y1s[i*TE + e] * pool[(O_T1 + d)*TE + e];
      accY[e] = 0.f;
    }
    #pragma unroll 2
    for (int k = 0; k < 64; ++k){
      float av[TE], cv[TE];
      ldact<TE>(&pool[(O_EV  + i*64 + k)*TE], av);
      ldact<TE>(&pool[(O_CRW + i*64 + k)*TE], cv);
      float w2 = l1Wv[(128 + k)*64 + d];
      float w3 = l1Wv[(192 + k)*64 + d];
      #pragma unroll
      for (int e = 0; e < TE; ++e){
        accY[e] = fmaf(av[e], w2, accY[e]);
        accP[e] = fmaf(cv[e], w3, accP[e]);
      }
    }
    #pragma unroll
    for (int e = 0; e < TE; ++e){
      float val = accP[e] + y0s[e]*accY[e];
      pool[(O_GV + i*64 + d)*TE + e] = val * pool[(O_GSB + d)*TE + e];
    }
  } else {
    gemv_t<TE,128,64,1,1>(PL, O_GSA, tid - 192,
      [=](int k,int j0,float* wv){ wv[0] = tp2w[128 + k] * l2Wv[k*64 + j0]; },
      [=](int j,int e,float v){ PL[(O_U1B + j)*TE + e] = v; });
  }
  __syncthreads();

  // P8: s2 -> A, fcr -> C (0..127, elementwise) || z,den (128..159)
  if (tid < 128){
    int e = tid & 7, p = tid >> 3;   // p 0..15
    float yy0 = y0s[e];
    float y10 = y1s[e], y11 = y1s[TE + e], y12 = y1s[2*TE + e];
    for (int c = p; c < 128; c += 16){
      pool[(O_S2 + c)*TE + e] = tp2w[c] * pool[(O_GSA + c)*TE + e] * yy0;
    }
    for (int c = p; c < 64; c += 16){
      float f0 = pool[(O_GV +       c)*TE + e];
      float f1 = pool[(O_GV + 64  + c)*TE + e];
      float f2 = pool[(O_GV + 128 + c)*TE + e];
      pool[(O_S2 + 128 + c)*TE + e] = tp2w[320 + c] * (f0*y10 + f1*y11 + f2*y12);
      pool[(O_FCR +       c)*TE + e] = f1*y12 - f2*y11;
      pool[(O_FCR + 64  + c)*TE + e] = f2*y10 - f0*y12;
      pool[(O_FCR + 128 + c)*TE + e] = f0*y11 - f1*y10;
    }
  } else if (tid < 160){
    int r = tid - 128, e = r & 7, h = r >> 3;
    float z = __expf(lg[h*TE + e]);            // max-free; logits O(few) << 88
    zl[h*TE + e] = z;
    atomAddF(&den[(size_t)dstI[e]*4 + h], z);
  }
  __syncthreads();

  // P9: val_s scatter (0..127, NJ1) || val_v scatter (128..223)
  if (tid < 128){
    gemv_t<TE,192,128,1,1>(PL, O_S2, tid,
      [=](int k,int j0,float* wv){ wv[0] = l2Ws[k*128 + j0]; },
      [=](int j,int e,float v){
        float vv = (l2bs[j] + v) * ZL[(j >> 5)*TE + e];
        atomAddF(&num_s[(size_t)DI[e]*128 + j], vv);
      });
  } else if (tid < 224){
    int r = tid - 128;
    int i = r / 32, d0 = (r % 32) * 2;
    float accP[TE][2], accY[TE][2];
    #pragma unroll
    for (int e = 0; e < TE; ++e){
      float y1v = y1s[i*TE + e];
      accP[e][0] = y1v * pool[(O_U1B + d0    )*TE + e];
      accP[e][1] = y1v * pool[(O_U1B + d0 + 1)*TE + e];
      accY[e][0] = 0.f; accY[e][1] = 0.f;
    }
    #pragma unroll 2
    for (int k = 0; k < 64; ++k){
      float av[TE], cv[TE];
      ldact<TE>(&pool[(O_GV  + i*64 + k)*TE], av);
      ldact<TE>(&pool[(O_FCR + i*64 + k)*TE], cv);
      float w2[2], w3[2];
      float s2c = tp2w[256 + k];
      float s3c = tp2w[384 + k];
      ldw2(l2Wv, (128 + k)*64 + d0, w2);
      ldw2(l2Wv, (192 + k)*64 + d0, w3);
      w2[0]*=s2c; w2[1]*=s2c; w3[0]*=s3c; w3[1]*=s3c;
      #pragma unroll
      for (int e = 0; e < TE; ++e){
        accY[e][0] = fmaf(av[e], w2[0], accY[e][0]);
        accY[e][1] = fmaf(av[e], w2[1], accY[e][1]);
        accP[e][0] = fmaf(cv[e], w3[0], accP[e][0]);
        accP[e][1] = fmaf(cv[e], w3[1], accP[e][1]);
      }
    }
    #pragma unroll
    for (int t = 0; t < 2; ++t){
      int d = d0 + t;
      int h = d >> 4;
      #pragma unroll
      for (int e = 0; e < TE; ++e){
        float val = accP[e][t] + y0s[e]*accY[e][t];
        atomAddF(&num_v[(size_t)dstI[e]*192 + i*64 + d], val * zl[h*TE + e]);
      }
    }
  }
}

// ---------------- kernel 3: normalize + output projections ----------------
__global__ __launch_bounds__(256) void k_node_out(
    const float* __restrict__ den, const float* __restrict__ num_s, const float* __restrict__ num_v,
    const float* __restrict__ Wos, const float* __restrict__ bos, const float* __restrict__ Wov,
    float* __restrict__ out)
{
  __shared__ __align__(16) float pl[320*NT];
  __shared__ float dl[4*NT];
  float* PL = pl;
  const int tid = threadIdx.x;
  const int n0 = blockIdx.x * NT;
  if (tid < 64){
    int e = tid & 15, h = tid >> 4;
    dl[h*NT + e] = den[(size_t)(n0 + e)*4 + h] + 1e-12f;
  }
  __syncthreads();
  {
    int e = tid & 15, p = tid >> 4;
    for (int c = p; c < 128; c += 16)
      pl[c*NT + e] = num_s[(size_t)(n0+e)*128 + c] / dl[(c >> 5)*NT + e];
    for (int c = p; c < 64; c += 16){
      float dd = dl[(c >> 4)*NT + e];
      pl[(128 +       c)*NT + e] = num_v[(size_t)(n0+e)*192 +       c] / dd;
      pl[(128 + 64  + c)*NT + e] = num_v[(size_t)(n0+e)*192 + 64  + c] / dd;
      pl[(128 + 128 + c)*NT + e] = num_v[(size_t)(n0+e)*192 + 128 + c] / dd;
    }
  }
  __syncthreads();
  gemv_t<NT,128,128,2,4>(PL, 0, tid,
    [=](int k,int j0,float* wv){ ldw2(Wos, k*128 + j0, wv); },
    [=](int j,int e,float v){ out[(size_t)(n0+e)*320 + j] = bos[j] + v; });
  #pragma unroll
  for (int i = 0; i < 3; ++i){
    gemv_t<NT,64,64,2,8>(PL, 128 + i*64, tid,
      [=](int k,int j0,float* wv){ ldw2(Wov, k*64 + j0, wv); },
      [=](int j,int e,float v){ out[(size_t)(n0+e)*320 + 128 + j*3 + i] = v; });
  }
}

extern "C" void kernel_launch(void* const* d_in, const int* in_sizes, int n_in,
                              void* d_out, int out_size, void* d_ws, size_t ws_size,
                              hipStream_t stream)
{
  const float* node_input = (const float*)d_in[0];
  const float* node_attr  = (const float*)d_in[1];
  const float* edge_attr  = (const float*)d_in[2];
  const float* edge_emb   = (const float*)d_in[3];
  const int* edge_src   = (const int*)d_in[4];
  const int* edge_dst   = (const int*)d_in[5];
  const float* W_src_s = (const float*)d_in[6];
  const float* b_src_s = (const float*)d_in[7];
  const float* W_src_v = (const float*)d_in[8];
  const float* W_dst_s = (const float*)d_in[9];
  const float* W_dst_v = (const float*)d_in[10];
  const float* rad_W0  = (const float*)d_in[11];
  const float* rad_b0  = (const float*)d_in[12];
  const float* rad_W1  = (const float*)d_in[13];
  const float* rad_b1  = (const float*)d_in[14];
  const float* rad_W2  = (const float*)d_in[15];
  const float* rad_b2  = (const float*)d_in[16];
  const float* lin1_Ws = (const float*)d_in[17];
  const float* lin1_bs = (const float*)d_in[18];
  const float* lin1_Wv = (const float*)d_in[19];
  const float* att_Ws  = (const float*)d_in[20];
  const float* att_bs  = (const float*)d_in[21];
  const float* tp2_w   = (const float*)d_in[22];
  const float* lin2_Ws = (const float*)d_in[23];
  const float* lin2_bs = (const float*)d_in[24];
  const float* lin2_Wv = (const float*)d_in[25];
  const float* att_dot = (const float*)d_in[26];
  const float* out_Ws  = (const float*)d_in[27];
  const float* out_bs  = (const float*)d_in[28];
  const float* out_Wv  = (const float*)d_in[29];

  const int nN = in_sizes[0] / 320;   // 10000
  const int nE = in_sizes[4];         // 320000

  float* ws    = (float*)d_ws;
  float* den   = ws;
  float* num_s = den   + (size_t)nN * 4;
  float* num_v = num_s + (size_t)nN * 128;
  float* msA   = num_v + (size_t)nN * 192;
  float* dsA   = msA   + (size_t)nN * 128;
  float* mvA   = dsA   + (size_t)nN * 128;
  float* dvA   = mvA   + (size_t)nN * 192;

  size_t need = ((size_t)nN * (4 + 128 + 192 + 128 + 128 + 192 + 192)) * sizeof(float);
  if (ws_size < need) return;  // fail loudly (output stays poisoned)

  hipMemsetAsync(den, 0, (size_t)nN * (4 + 128 + 192) * sizeof(float), stream);

  k_node_pre<<<nN/NT, 256, 0, stream>>>(node_input, W_src_s, b_src_s, W_src_v,
                                        W_dst_s, W_dst_v, msA, dsA, mvA, dvA);
  k_edge<<<nE/TE, 256, 0, stream>>>(edge_attr, edge_emb, edge_src, edge_dst, node_attr,
                                    msA, dsA, mvA, dvA,
                                    rad_W0, rad_b0, rad_W1, rad_b1, rad_W2, rad_b2,
                                    lin1_Ws, lin1_bs, lin1_Wv,
                                    att_Ws, att_bs, att_dot,
                                    tp2_w, lin2_Ws, lin2_bs, lin2_Wv,
                                    den, num_s, num_v);
  k_node_out<<<nN/NT, 256, 0, stream>>>(den, num_s, num_v, out_Ws, out_bs, out_Wv,
                                        (float*)d_out);
}